// Round 8
// baseline (548.958 us; speedup 1.0000x reference)
//
#include <hip/hip_runtime.h>
#include <cstddef>
#include <cstdint>

#define Hdim 1024
#define Bdim 64
#define Idim 128

// BETA = 10.0 / 0.192
#define BETA_F 52.083333333333336f
#define INV_BETA_F 0.0192f
#define LN2_F 0.6931471805599453f

__device__ __forceinline__ float sigf(float x) {
    return 1.0f / (1.0f + __expf(-x));
}

// log(cosh(t)) = |t| + log1p(exp(-2|t|)) - ln2   (stable, matches fp32 ref)
__device__ __forceinline__ float logcoshf_(float t) {
    float a = fabsf(t);
    return a + log1pf(__expf(-2.0f * a)) - LN2_F;
}

// ---------------------------------------------------------------------------
// Pre-kernel: rates r = sigmoid(v_t), membx = p_r@x + b_r, gatex = |p_r|@x+g_z
// ---------------------------------------------------------------------------
__global__ void pre_kernel(const float* __restrict__ x,
                           const float* __restrict__ v_t,
                           const float* __restrict__ p_r,
                           const float* __restrict__ b_r,
                           const float* __restrict__ g_z,
                           float* __restrict__ r_ws,
                           float* __restrict__ membx,
                           float* __restrict__ gatex) {
    const int j = blockIdx.x;   // 0..H-1
    const int b = threadIdx.x;  // 0..B-1
    const float* pr = p_r + (size_t)j * Idim;
    float accm = 0.0f, accg = 0.0f;
#pragma unroll 4
    for (int i = 0; i < Idim; ++i) {
        float p  = pr[i];              // wave-uniform -> scalar load
        float xv = x[i * Bdim + b];    // coalesced
        accm = fmaf(p, xv, accm);
        accg = fmaf(fabsf(p), xv, accg);
    }
    membx[j * Bdim + b] = accm + b_r[j];
    gatex[j * Bdim + b] = accg + g_z[j];

    int id = j * Bdim + b;  // 0..65535
    r_ws[id] = sigf(v_t[id]);
}

// ---------------------------------------------------------------------------
// Main kernel: TWO rows per block (grid=512): block handles rows j0=2*bid,
// j1=j0+1 for all 64 batches; 4 waves x 16 batches.
//
// Rationale (rounds 0..7): 8 structural variants all land 162-190 µs across
// occupancy 21-44% — per-CU VMEM read throughput (~8 B/cyc/CU measured,
// ~10 B/cyc ceiling) is the binding resource, not latency. Traffic per
// (block,batch) was X 4K + U 4K + rv 4K; the rv row (r_ws[b][:]) re-read is
// 1/3 of all traffic. Two rows per block load rv ONCE and reuse it
// in-register for both rows' dot products: 3.0 -> 2.5 MiB/CU (-17%).
//
// __launch_bounds__(256,2): VGPR budget 128 (empirical: (256,N) caps at
// 512/2N; a 64-cap spills this body — round-3 lesson). ~95 VGPR -> 2
// waves/SIMD; occupancy invariance across rounds says that's fine.
// ---------------------------------------------------------------------------
__global__ __launch_bounds__(256, 2) void main_kernel(
    const float* __restrict__ X,
    const float* __restrict__ U,
    const float* __restrict__ raw_w_r,
    const float* __restrict__ c_x,
    const float* __restrict__ c_u,
    const float* __restrict__ c_U,
    const float* __restrict__ v_t,
    const float* __restrict__ a_exc,
    const float* __restrict__ a_inh,
    const float* __restrict__ r_ws,
    const float* __restrict__ membx,
    const float* __restrict__ gatex,
    float* __restrict__ out) {
    __shared__ __align__(16) float s_zx[2][Hdim];
    __shared__ __align__(16) float s_zu[2][Hdim];
    __shared__ __align__(16) float s_uc[2][Hdim];
    __shared__ __align__(16) float s_wr[2][Hdim];

    const int j0  = blockIdx.x * 2;
    const int tid = threadIdx.x;

    const float Aexc = 10.0f * sigf(a_exc[0]);
    const float Ainh = 10.0f * sigf(a_inh[0]);

    // ---- stage per-row transforms for BOTH rows (512 float4s per array) ----
#pragma unroll
    for (int f = tid; f < 512; f += 256) {
        const int row = f >> 8;          // 0 or 1
        const int k   = (f & 255) * 4;   // 0..1020
        const size_t ro = (size_t)(j0 + row) * Hdim + k;
        float4 rw = *(const float4*)(raw_w_r + ro);
        float4 cx = *(const float4*)(c_x + ro);
        float4 cu = *(const float4*)(c_u + ro);
        float4 cN = *(const float4*)(c_U + ro);

        s_wr[row][k + 0] = logcoshf_(BETA_F * rw.x) * INV_BETA_F;
        s_wr[row][k + 1] = logcoshf_(BETA_F * rw.y) * INV_BETA_F;
        s_wr[row][k + 2] = logcoshf_(BETA_F * rw.z) * INV_BETA_F;
        s_wr[row][k + 3] = logcoshf_(BETA_F * rw.w) * INV_BETA_F;

        s_zx[row][k + 0] = 0.001f + 0.099f * sigf(cx.x);
        s_zx[row][k + 1] = 0.001f + 0.099f * sigf(cx.y);
        s_zx[row][k + 2] = 0.001f + 0.099f * sigf(cx.z);
        s_zx[row][k + 3] = 0.001f + 0.099f * sigf(cx.w);

        s_zu[row][k + 0] = 0.001f + 0.099f * sigf(cu.x);
        s_zu[row][k + 1] = 0.001f + 0.099f * sigf(cu.y);
        s_zu[row][k + 2] = 0.001f + 0.099f * sigf(cu.z);
        s_zu[row][k + 3] = 0.001f + 0.099f * sigf(cu.w);

        s_uc[row][k + 0] = 0.9f * sigf(cN.x);
        s_uc[row][k + 1] = 0.9f * sigf(cN.y);
        s_uc[row][k + 2] = 0.9f * sigf(cN.z);
        s_uc[row][k + 3] = 0.9f * sigf(cN.w);
    }
    __syncthreads();

    const int wave = tid >> 6;
    const int lane = tid & 63;

    for (int b = wave; b < Bdim; b += 4) {
        const float* Xb = X + (size_t)b * Hdim * Hdim + (size_t)j0 * Hdim;
        const float* Ub = U + (size_t)b * Hdim * Hdim + (size_t)j0 * Hdim;
        const float* rb = r_ws + b * Hdim;
        const float rj0 = rb[j0];      // r[j0,b]
        const float rj1 = rb[j0 + 1];  // r[j1,b]

        float rec0 = 0.0f, gate0 = 0.0f;
        float rec1 = 0.0f, gate1 = 0.0f;
#pragma unroll 2
        for (int it = 0; it < 4; ++it) {
            const float Ah = (it < 2) ? Aexc : Ainh;  // k<512 : k>=512
            const int k = it * 256 + lane * 4;
            float4 rv  = *(const float4*)(rb + k);          // loaded ONCE,
            float4 Xv0 = *(const float4*)(Xb + k);          // used by 2 rows
            float4 Xv1 = *(const float4*)(Xb + Hdim + k);
            float4 Uv0 = *(const float4*)(Ub + k);
            float4 Uv1 = *(const float4*)(Ub + Hdim + k);
            float4 zx0 = *(const float4*)(&s_zx[0][k]);
            float4 zx1 = *(const float4*)(&s_zx[1][k]);
            float4 zu0 = *(const float4*)(&s_zu[0][k]);
            float4 zu1 = *(const float4*)(&s_zu[1][k]);
            float4 uc0 = *(const float4*)(&s_uc[0][k]);
            float4 uc1 = *(const float4*)(&s_uc[1][k]);
            float4 wr0 = *(const float4*)(&s_wr[0][k]);
            float4 wr1 = *(const float4*)(&s_wr[1][k]);

#define COMPONENT(c, Xv, Uv, zx, zu, uc, wr, rj, rec, gate)                   \
    {                                                                         \
        float xn = zx.c + (1.0f - zx.c) * Xv.c - Uv.c * Xv.c * rj;            \
        float un = uc.c * zu.c + (1.0f - zu.c) * Uv.c +                       \
                   uc.c * (1.0f - Uv.c) * rj;                                 \
        un = fminf(fmaxf(un, uc.c), 1.0f);                                    \
        rec  = fmaf(xn * un * wr.c, rv.c, rec);                               \
        gate = fmaf(wr.c * Ah, rv.c, gate);                                   \
    }
            COMPONENT(x, Xv0, Uv0, zx0, zu0, uc0, wr0, rj0, rec0, gate0)
            COMPONENT(y, Xv0, Uv0, zx0, zu0, uc0, wr0, rj0, rec0, gate0)
            COMPONENT(z, Xv0, Uv0, zx0, zu0, uc0, wr0, rj0, rec0, gate0)
            COMPONENT(w, Xv0, Uv0, zx0, zu0, uc0, wr0, rj0, rec0, gate0)
            COMPONENT(x, Xv1, Uv1, zx1, zu1, uc1, wr1, rj1, rec1, gate1)
            COMPONENT(y, Xv1, Uv1, zx1, zu1, uc1, wr1, rj1, rec1, gate1)
            COMPONENT(z, Xv1, Uv1, zx1, zu1, uc1, wr1, rj1, rec1, gate1)
            COMPONENT(w, Xv1, Uv1, zx1, zu1, uc1, wr1, rj1, rec1, gate1)
#undef COMPONENT
        }

        // uniform tail loads before the reduce (L2-resident)
        const float vt0 = v_t[(size_t)b * Hdim + j0];
        const float vt1 = v_t[(size_t)b * Hdim + j0 + 1];
        const float gx0 = gatex[j0 * Bdim + b];
        const float gx1 = gatex[(j0 + 1) * Bdim + b];
        const float mx0 = membx[j0 * Bdim + b];
        const float mx1 = membx[(j0 + 1) * Bdim + b];

        // butterfly reduce across the 64-lane wave
#pragma unroll
        for (int off = 32; off > 0; off >>= 1) {
            rec0  += __shfl_xor(rec0, off, 64);
            gate0 += __shfl_xor(gate0, off, 64);
            rec1  += __shfl_xor(rec1, off, 64);
            gate1 += __shfl_xor(gate1, off, 64);
        }

        if (lane == 0) {
            float z0 = 0.1f * sigf(gate0 + gx0);
            out[(size_t)b * Hdim + j0] =
                (1.0f - z0) * vt0 + 0.1f * (rec0 + mx0);
            float z1 = 0.1f * sigf(gate1 + gx1);
            out[(size_t)b * Hdim + j0 + 1] =
                (1.0f - z1) * vt1 + 0.1f * (rec1 + mx1);
        }
    }
}

extern "C" void kernel_launch(void* const* d_in, const int* in_sizes, int n_in,
                              void* d_out, int out_size, void* d_ws, size_t ws_size,
                              hipStream_t stream) {
    const float* x       = (const float*)d_in[0];   // (I,B)
    const float* v_t     = (const float*)d_in[1];   // (B,H)
    const float* X       = (const float*)d_in[2];   // (B,H,H)
    const float* U       = (const float*)d_in[3];   // (B,H,H)
    const float* raw_w_r = (const float*)d_in[4];   // (H,H)
    const float* p_r     = (const float*)d_in[5];   // (H,I)
    const float* b_r     = (const float*)d_in[6];   // (H,1)
    const float* g_z     = (const float*)d_in[7];   // (H,1)
    const float* c_x     = (const float*)d_in[8];   // (H,H)
    const float* c_u     = (const float*)d_in[9];   // (H,H)
    const float* c_U     = (const float*)d_in[10];  // (H,H)
    const float* a_exc   = (const float*)d_in[11];  // scalar
    const float* a_inh   = (const float*)d_in[12];  // scalar

    float* out = (float*)d_out;  // (B,H) fp32

    float* r_ws  = (float*)d_ws;              // B*H
    float* membx = r_ws + Bdim * Hdim;        // H*B
    float* gatex = membx + Hdim * Bdim;       // H*B

    pre_kernel<<<dim3(Hdim), dim3(Bdim), 0, stream>>>(
        x, v_t, p_r, b_r, g_z, r_ws, membx, gatex);

    main_kernel<<<dim3(Hdim / 2), dim3(256), 0, stream>>>(
        X, U, raw_w_r, c_x, c_u, c_U, v_t, a_exc, a_inh,
        r_ws, membx, gatex, out);
}

// Round 10
// 531.856 us; speedup vs baseline: 1.0322x; 1.0322x over previous
//
#include <hip/hip_runtime.h>
#include <cstddef>
#include <cstdint>

#define Hdim 1024
#define Bdim 64
#define Idim 128

// BETA = 10.0 / 0.192
#define BETA_F 52.083333333333336f
#define INV_BETA_F 0.0192f
#define LN2_F 0.6931471805599453f

// clang native vector type — __builtin_nontemporal_load requires a pointer
// to scalar/native-vector, NOT HIP_vector_type (round-9 compile error).
typedef float floatx4 __attribute__((ext_vector_type(4)));

__device__ __forceinline__ float sigf(float x) {
    return 1.0f / (1.0f + __expf(-x));
}

// log(cosh(t)) = |t| + log1p(exp(-2|t|)) - ln2   (stable, matches fp32 ref)
__device__ __forceinline__ float logcoshf_(float t) {
    float a = fabsf(t);
    return a + log1pf(__expf(-2.0f * a)) - LN2_F;
}

// Non-temporal float4 load: sets the `nt` cache bit on global_load_dwordx4.
// X/U are read exactly once (pure stream); nt avoids LLC allocation ->
// no dirty-line evictions/writebacks behind the read stream (the harness
// re-poison fill leaves LLC 100% dirty with X/U lines).
__device__ __forceinline__ floatx4 ldnt4(const float* p) {
    return __builtin_nontemporal_load((const floatx4*)p);
}

// ---------------------------------------------------------------------------
// Pre-kernel: rates r = sigmoid(v_t), membx = p_r@x + b_r, gatex = |p_r|@x+g_z
// ---------------------------------------------------------------------------
__global__ void pre_kernel(const float* __restrict__ x,
                           const float* __restrict__ v_t,
                           const float* __restrict__ p_r,
                           const float* __restrict__ b_r,
                           const float* __restrict__ g_z,
                           float* __restrict__ r_ws,
                           float* __restrict__ membx,
                           float* __restrict__ gatex) {
    const int j = blockIdx.x;   // 0..H-1
    const int b = threadIdx.x;  // 0..B-1
    const float* pr = p_r + (size_t)j * Idim;
    float accm = 0.0f, accg = 0.0f;
#pragma unroll 4
    for (int i = 0; i < Idim; ++i) {
        float p  = pr[i];              // wave-uniform -> scalar load
        float xv = x[i * Bdim + b];    // coalesced
        accm = fmaf(p, xv, accm);
        accg = fmaf(fabsf(p), xv, accg);
    }
    membx[j * Bdim + b] = accm + b_r[j];
    gatex[j * Bdim + b] = accg + g_z[j];

    int id = j * Bdim + b;  // 0..65535
    r_ws[id] = sigf(v_t[id]);
}

// ---------------------------------------------------------------------------
// Main kernel: TWO rows per block (grid=512), 4 waves x 16 batches.
// Identical to round 8 EXCEPT X/U loads are non-temporal (single change,
// theory-bearing): rounds 0-8 showed time is invariant (163±5 µs) to
// occupancy/VGPR/DMA/traffic — only the X+U miss stream matters. FETCH
// (273 MB) < X+U unique (537 MB): ~half is served by a 100%-dirty LLC
// (harness fill), so every LLC miss evicts+writes back a dirty line,
// throttling the read stream to ~3.3 TB/s on a machine that fills at 6.5.
// nt loads bypass LLC allocation -> pure read stream, no writebacks.
// ---------------------------------------------------------------------------
__global__ __launch_bounds__(256, 2) void main_kernel(
    const float* __restrict__ X,
    const float* __restrict__ U,
    const float* __restrict__ raw_w_r,
    const float* __restrict__ c_x,
    const float* __restrict__ c_u,
    const float* __restrict__ c_U,
    const float* __restrict__ v_t,
    const float* __restrict__ a_exc,
    const float* __restrict__ a_inh,
    const float* __restrict__ r_ws,
    const float* __restrict__ membx,
    const float* __restrict__ gatex,
    float* __restrict__ out) {
    __shared__ __align__(16) float s_zx[2][Hdim];
    __shared__ __align__(16) float s_zu[2][Hdim];
    __shared__ __align__(16) float s_uc[2][Hdim];
    __shared__ __align__(16) float s_wr[2][Hdim];

    const int j0  = blockIdx.x * 2;
    const int tid = threadIdx.x;

    const float Aexc = 10.0f * sigf(a_exc[0]);
    const float Ainh = 10.0f * sigf(a_inh[0]);

    // ---- stage per-row transforms for BOTH rows (512 float4s per array) ----
#pragma unroll
    for (int f = tid; f < 512; f += 256) {
        const int row = f >> 8;          // 0 or 1
        const int k   = (f & 255) * 4;   // 0..1020
        const size_t ro = (size_t)(j0 + row) * Hdim + k;
        float4 rw = *(const float4*)(raw_w_r + ro);
        float4 cx = *(const float4*)(c_x + ro);
        float4 cu = *(const float4*)(c_u + ro);
        float4 cN = *(const float4*)(c_U + ro);

        s_wr[row][k + 0] = logcoshf_(BETA_F * rw.x) * INV_BETA_F;
        s_wr[row][k + 1] = logcoshf_(BETA_F * rw.y) * INV_BETA_F;
        s_wr[row][k + 2] = logcoshf_(BETA_F * rw.z) * INV_BETA_F;
        s_wr[row][k + 3] = logcoshf_(BETA_F * rw.w) * INV_BETA_F;

        s_zx[row][k + 0] = 0.001f + 0.099f * sigf(cx.x);
        s_zx[row][k + 1] = 0.001f + 0.099f * sigf(cx.y);
        s_zx[row][k + 2] = 0.001f + 0.099f * sigf(cx.z);
        s_zx[row][k + 3] = 0.001f + 0.099f * sigf(cx.w);

        s_zu[row][k + 0] = 0.001f + 0.099f * sigf(cu.x);
        s_zu[row][k + 1] = 0.001f + 0.099f * sigf(cu.y);
        s_zu[row][k + 2] = 0.001f + 0.099f * sigf(cu.z);
        s_zu[row][k + 3] = 0.001f + 0.099f * sigf(cu.w);

        s_uc[row][k + 0] = 0.9f * sigf(cN.x);
        s_uc[row][k + 1] = 0.9f * sigf(cN.y);
        s_uc[row][k + 2] = 0.9f * sigf(cN.z);
        s_uc[row][k + 3] = 0.9f * sigf(cN.w);
    }
    __syncthreads();

    const int wave = tid >> 6;
    const int lane = tid & 63;

    for (int b = wave; b < Bdim; b += 4) {
        const float* Xb = X + (size_t)b * Hdim * Hdim + (size_t)j0 * Hdim;
        const float* Ub = U + (size_t)b * Hdim * Hdim + (size_t)j0 * Hdim;
        const float* rb = r_ws + b * Hdim;
        const float rj0 = rb[j0];      // r[j0,b]
        const float rj1 = rb[j0 + 1];  // r[j1,b]

        float rec0 = 0.0f, gate0 = 0.0f;
        float rec1 = 0.0f, gate1 = 0.0f;
#pragma unroll 2
        for (int it = 0; it < 4; ++it) {
            const float Ah = (it < 2) ? Aexc : Ainh;  // k<512 : k>=512
            const int k = it * 256 + lane * 4;
            float4 rv   = *(const float4*)(rb + k);  // cached (L2-resident)
            floatx4 Xv0 = ldnt4(Xb + k);             // nt: stream, no LLC alloc
            floatx4 Xv1 = ldnt4(Xb + Hdim + k);
            floatx4 Uv0 = ldnt4(Ub + k);
            floatx4 Uv1 = ldnt4(Ub + Hdim + k);
            float4 zx0 = *(const float4*)(&s_zx[0][k]);
            float4 zx1 = *(const float4*)(&s_zx[1][k]);
            float4 zu0 = *(const float4*)(&s_zu[0][k]);
            float4 zu1 = *(const float4*)(&s_zu[1][k]);
            float4 uc0 = *(const float4*)(&s_uc[0][k]);
            float4 uc1 = *(const float4*)(&s_uc[1][k]);
            float4 wr0 = *(const float4*)(&s_wr[0][k]);
            float4 wr1 = *(const float4*)(&s_wr[1][k]);

// ext_vector uses [i]; float4 uses .x/.y/.z/.w — map via component index
#define COMPONENT(ci, c, Xv, Uv, zx, zu, uc, wr, rj, rec, gate)               \
    {                                                                         \
        float Xs = Xv[ci], Us = Uv[ci];                                       \
        float xn = zx.c + (1.0f - zx.c) * Xs - Us * Xs * rj;                  \
        float un = uc.c * zu.c + (1.0f - zu.c) * Us +                         \
                   uc.c * (1.0f - Us) * rj;                                   \
        un = fminf(fmaxf(un, uc.c), 1.0f);                                    \
        rec  = fmaf(xn * un * wr.c, rv.c, rec);                               \
        gate = fmaf(wr.c * Ah, rv.c, gate);                                   \
    }
            COMPONENT(0, x, Xv0, Uv0, zx0, zu0, uc0, wr0, rj0, rec0, gate0)
            COMPONENT(1, y, Xv0, Uv0, zx0, zu0, uc0, wr0, rj0, rec0, gate0)
            COMPONENT(2, z, Xv0, Uv0, zx0, zu0, uc0, wr0, rj0, rec0, gate0)
            COMPONENT(3, w, Xv0, Uv0, zx0, zu0, uc0, wr0, rj0, rec0, gate0)
            COMPONENT(0, x, Xv1, Uv1, zx1, zu1, uc1, wr1, rj1, rec1, gate1)
            COMPONENT(1, y, Xv1, Uv1, zx1, zu1, uc1, wr1, rj1, rec1, gate1)
            COMPONENT(2, z, Xv1, Uv1, zx1, zu1, uc1, wr1, rj1, rec1, gate1)
            COMPONENT(3, w, Xv1, Uv1, zx1, zu1, uc1, wr1, rj1, rec1, gate1)
#undef COMPONENT
        }

        // uniform tail loads before the reduce (L2-resident)
        const float vt0 = v_t[(size_t)b * Hdim + j0];
        const float vt1 = v_t[(size_t)b * Hdim + j0 + 1];
        const float gx0 = gatex[j0 * Bdim + b];
        const float gx1 = gatex[(j0 + 1) * Bdim + b];
        const float mx0 = membx[j0 * Bdim + b];
        const float mx1 = membx[(j0 + 1) * Bdim + b];

        // butterfly reduce across the 64-lane wave
#pragma unroll
        for (int off = 32; off > 0; off >>= 1) {
            rec0  += __shfl_xor(rec0, off, 64);
            gate0 += __shfl_xor(gate0, off, 64);
            rec1  += __shfl_xor(rec1, off, 64);
            gate1 += __shfl_xor(gate1, off, 64);
        }

        if (lane == 0) {
            float z0 = 0.1f * sigf(gate0 + gx0);
            out[(size_t)b * Hdim + j0] =
                (1.0f - z0) * vt0 + 0.1f * (rec0 + mx0);
            float z1 = 0.1f * sigf(gate1 + gx1);
            out[(size_t)b * Hdim + j0 + 1] =
                (1.0f - z1) * vt1 + 0.1f * (rec1 + mx1);
        }
    }
}

extern "C" void kernel_launch(void* const* d_in, const int* in_sizes, int n_in,
                              void* d_out, int out_size, void* d_ws, size_t ws_size,
                              hipStream_t stream) {
    const float* x       = (const float*)d_in[0];   // (I,B)
    const float* v_t     = (const float*)d_in[1];   // (B,H)
    const float* X       = (const float*)d_in[2];   // (B,H,H)
    const float* U       = (const float*)d_in[3];   // (B,H,H)
    const float* raw_w_r = (const float*)d_in[4];   // (H,H)
    const float* p_r     = (const float*)d_in[5];   // (H,I)
    const float* b_r     = (const float*)d_in[6];   // (H,1)
    const float* g_z     = (const float*)d_in[7];   // (H,1)
    const float* c_x     = (const float*)d_in[8];   // (H,H)
    const float* c_u     = (const float*)d_in[9];   // (H,H)
    const float* c_U     = (const float*)d_in[10];  // (H,H)
    const float* a_exc   = (const float*)d_in[11];  // scalar
    const float* a_inh   = (const float*)d_in[12];  // scalar

    float* out = (float*)d_out;  // (B,H) fp32

    float* r_ws  = (float*)d_ws;              // B*H
    float* membx = r_ws + Bdim * Hdim;        // H*B
    float* gatex = membx + Hdim * Bdim;       // H*B

    pre_kernel<<<dim3(Hdim), dim3(Bdim), 0, stream>>>(
        x, v_t, p_r, b_r, g_z, r_ws, membx, gatex);

    main_kernel<<<dim3(Hdim / 2), dim3(256), 0, stream>>>(
        X, U, raw_w_r, c_x, c_u, c_U, v_t, a_exc, a_inh,
        r_ws, membx, gatex, out);
}

// Round 11
// 526.009 us; speedup vs baseline: 1.0436x; 1.0111x over previous
//
#include <hip/hip_runtime.h>
#include <cstddef>
#include <cstdint>

#define Hdim 1024
#define Bdim 64
#define Idim 128

// BETA = 10.0 / 0.192
#define BETA_F 52.083333333333336f
#define INV_BETA_F 0.0192f
#define LN2_F 0.6931471805599453f

// clang native vector type — __builtin_nontemporal_load requires a pointer
// to scalar/native-vector, NOT HIP_vector_type (round-9 compile error).
typedef float floatx4 __attribute__((ext_vector_type(4)));

__device__ __forceinline__ float sigf(float x) {
    return 1.0f / (1.0f + __expf(-x));
}

// log(cosh(t)) = |t| + log1p(exp(-2|t|)) - ln2   (stable, matches fp32 ref)
__device__ __forceinline__ float logcoshf_(float t) {
    float a = fabsf(t);
    return a + log1pf(__expf(-2.0f * a)) - LN2_F;
}

// Non-temporal float4 load (`nt` bit): X/U are read exactly once; nt skips
// LLC allocation -> no dirty-line evictions/writebacks behind the stream.
// Round 10 verified: main_kernel 163 -> ~146 µs from this alone.
__device__ __forceinline__ floatx4 ldnt4(const float* p) {
    return __builtin_nontemporal_load((const floatx4*)p);
}

// ---------------------------------------------------------------------------
// Pre-kernel: rates r = sigmoid(v_t), membx = p_r@x + b_r, gatex = |p_r|@x+g_z
// ---------------------------------------------------------------------------
__global__ void pre_kernel(const float* __restrict__ x,
                           const float* __restrict__ v_t,
                           const float* __restrict__ p_r,
                           const float* __restrict__ b_r,
                           const float* __restrict__ g_z,
                           float* __restrict__ r_ws,
                           float* __restrict__ membx,
                           float* __restrict__ gatex) {
    const int j = blockIdx.x;   // 0..H-1
    const int b = threadIdx.x;  // 0..B-1
    const float* pr = p_r + (size_t)j * Idim;
    float accm = 0.0f, accg = 0.0f;
#pragma unroll 4
    for (int i = 0; i < Idim; ++i) {
        float p  = pr[i];              // wave-uniform -> scalar load
        float xv = x[i * Bdim + b];    // coalesced
        accm = fmaf(p, xv, accm);
        accg = fmaf(fabsf(p), xv, accg);
    }
    membx[j * Bdim + b] = accm + b_r[j];
    gatex[j * Bdim + b] = accg + g_z[j];

    int id = j * Bdim + b;  // 0..65535
    r_ws[id] = sigf(v_t[id]);
}

// ---------------------------------------------------------------------------
// Main kernel: grid = 1024 blocks = (row-pair, batch-half). Block handles
// rows j0, j0+1 for 32 of the 64 batches; 4 waves x 8 batches.
// Inner loop identical to round 10 (nt X/U loads, rv reuse across 2 rows).
//
// Post-nt concurrency fix: round 8/10's grid of 512 gave only 2 blocks/CU
// (8 waves/CU) — a GRID artifact. Pre-nt this didn't matter (LLC-writeback
// drag capped everything); post-nt the stream is clean, so double the
// resident waves: 4 blocks/CU x 4 waves = 16 waves/CU.
// LDS 32 KiB x 4 blocks = 128 KiB <= 160. VGPR 52 (r8 measured) fits the
// (256,4) cap of 64 without spill.
// ---------------------------------------------------------------------------
__global__ __launch_bounds__(256, 4) void main_kernel(
    const float* __restrict__ X,
    const float* __restrict__ U,
    const float* __restrict__ raw_w_r,
    const float* __restrict__ c_x,
    const float* __restrict__ c_u,
    const float* __restrict__ c_U,
    const float* __restrict__ v_t,
    const float* __restrict__ a_exc,
    const float* __restrict__ a_inh,
    const float* __restrict__ r_ws,
    const float* __restrict__ membx,
    const float* __restrict__ gatex,
    float* __restrict__ out) {
    __shared__ __align__(16) float s_zx[2][Hdim];
    __shared__ __align__(16) float s_zu[2][Hdim];
    __shared__ __align__(16) float s_uc[2][Hdim];
    __shared__ __align__(16) float s_wr[2][Hdim];

    const int j0    = (blockIdx.x >> 1) * 2;            // row pair
    const int bbase = (blockIdx.x & 1) * (Bdim / 2);    // batch half
    const int tid   = threadIdx.x;

    const float Aexc = 10.0f * sigf(a_exc[0]);
    const float Ainh = 10.0f * sigf(a_inh[0]);

    // ---- stage per-row transforms for BOTH rows (512 float4s per array) ----
#pragma unroll
    for (int f = tid; f < 512; f += 256) {
        const int row = f >> 8;          // 0 or 1
        const int k   = (f & 255) * 4;   // 0..1020
        const size_t ro = (size_t)(j0 + row) * Hdim + k;
        float4 rw = *(const float4*)(raw_w_r + ro);
        float4 cx = *(const float4*)(c_x + ro);
        float4 cu = *(const float4*)(c_u + ro);
        float4 cN = *(const float4*)(c_U + ro);

        s_wr[row][k + 0] = logcoshf_(BETA_F * rw.x) * INV_BETA_F;
        s_wr[row][k + 1] = logcoshf_(BETA_F * rw.y) * INV_BETA_F;
        s_wr[row][k + 2] = logcoshf_(BETA_F * rw.z) * INV_BETA_F;
        s_wr[row][k + 3] = logcoshf_(BETA_F * rw.w) * INV_BETA_F;

        s_zx[row][k + 0] = 0.001f + 0.099f * sigf(cx.x);
        s_zx[row][k + 1] = 0.001f + 0.099f * sigf(cx.y);
        s_zx[row][k + 2] = 0.001f + 0.099f * sigf(cx.z);
        s_zx[row][k + 3] = 0.001f + 0.099f * sigf(cx.w);

        s_zu[row][k + 0] = 0.001f + 0.099f * sigf(cu.x);
        s_zu[row][k + 1] = 0.001f + 0.099f * sigf(cu.y);
        s_zu[row][k + 2] = 0.001f + 0.099f * sigf(cu.z);
        s_zu[row][k + 3] = 0.001f + 0.099f * sigf(cu.w);

        s_uc[row][k + 0] = 0.9f * sigf(cN.x);
        s_uc[row][k + 1] = 0.9f * sigf(cN.y);
        s_uc[row][k + 2] = 0.9f * sigf(cN.z);
        s_uc[row][k + 3] = 0.9f * sigf(cN.w);
    }
    __syncthreads();

    const int wave = tid >> 6;
    const int lane = tid & 63;

    for (int bo = wave; bo < Bdim / 2; bo += 4) {
        const int b = bbase + bo;
        const float* Xb = X + (size_t)b * Hdim * Hdim + (size_t)j0 * Hdim;
        const float* Ub = U + (size_t)b * Hdim * Hdim + (size_t)j0 * Hdim;
        const float* rb = r_ws + b * Hdim;
        const float rj0 = rb[j0];      // r[j0,b]
        const float rj1 = rb[j0 + 1];  // r[j1,b]

        float rec0 = 0.0f, gate0 = 0.0f;
        float rec1 = 0.0f, gate1 = 0.0f;
#pragma unroll 2
        for (int it = 0; it < 4; ++it) {
            const float Ah = (it < 2) ? Aexc : Ainh;  // k<512 : k>=512
            const int k = it * 256 + lane * 4;
            float4 rv   = *(const float4*)(rb + k);  // cached (L2-resident)
            floatx4 Xv0 = ldnt4(Xb + k);             // nt: stream, no LLC alloc
            floatx4 Xv1 = ldnt4(Xb + Hdim + k);
            floatx4 Uv0 = ldnt4(Ub + k);
            floatx4 Uv1 = ldnt4(Ub + Hdim + k);
            float4 zx0 = *(const float4*)(&s_zx[0][k]);
            float4 zx1 = *(const float4*)(&s_zx[1][k]);
            float4 zu0 = *(const float4*)(&s_zu[0][k]);
            float4 zu1 = *(const float4*)(&s_zu[1][k]);
            float4 uc0 = *(const float4*)(&s_uc[0][k]);
            float4 uc1 = *(const float4*)(&s_uc[1][k]);
            float4 wr0 = *(const float4*)(&s_wr[0][k]);
            float4 wr1 = *(const float4*)(&s_wr[1][k]);

// ext_vector uses [i]; float4 uses .x/.y/.z/.w — map via component index
#define COMPONENT(ci, c, Xv, Uv, zx, zu, uc, wr, rj, rec, gate)               \
    {                                                                         \
        float Xs = Xv[ci], Us = Uv[ci];                                       \
        float xn = zx.c + (1.0f - zx.c) * Xs - Us * Xs * rj;                  \
        float un = uc.c * zu.c + (1.0f - zu.c) * Us +                         \
                   uc.c * (1.0f - Us) * rj;                                   \
        un = fminf(fmaxf(un, uc.c), 1.0f);                                    \
        rec  = fmaf(xn * un * wr.c, rv.c, rec);                               \
        gate = fmaf(wr.c * Ah, rv.c, gate);                                   \
    }
            COMPONENT(0, x, Xv0, Uv0, zx0, zu0, uc0, wr0, rj0, rec0, gate0)
            COMPONENT(1, y, Xv0, Uv0, zx0, zu0, uc0, wr0, rj0, rec0, gate0)
            COMPONENT(2, z, Xv0, Uv0, zx0, zu0, uc0, wr0, rj0, rec0, gate0)
            COMPONENT(3, w, Xv0, Uv0, zx0, zu0, uc0, wr0, rj0, rec0, gate0)
            COMPONENT(0, x, Xv1, Uv1, zx1, zu1, uc1, wr1, rj1, rec1, gate1)
            COMPONENT(1, y, Xv1, Uv1, zx1, zu1, uc1, wr1, rj1, rec1, gate1)
            COMPONENT(2, z, Xv1, Uv1, zx1, zu1, uc1, wr1, rj1, rec1, gate1)
            COMPONENT(3, w, Xv1, Uv1, zx1, zu1, uc1, wr1, rj1, rec1, gate1)
#undef COMPONENT
        }

        // uniform tail loads before the reduce (L2-resident)
        const float vt0 = v_t[(size_t)b * Hdim + j0];
        const float vt1 = v_t[(size_t)b * Hdim + j0 + 1];
        const float gx0 = gatex[j0 * Bdim + b];
        const float gx1 = gatex[(j0 + 1) * Bdim + b];
        const float mx0 = membx[j0 * Bdim + b];
        const float mx1 = membx[(j0 + 1) * Bdim + b];

        // butterfly reduce across the 64-lane wave
#pragma unroll
        for (int off = 32; off > 0; off >>= 1) {
            rec0  += __shfl_xor(rec0, off, 64);
            gate0 += __shfl_xor(gate0, off, 64);
            rec1  += __shfl_xor(rec1, off, 64);
            gate1 += __shfl_xor(gate1, off, 64);
        }

        if (lane == 0) {
            float z0 = 0.1f * sigf(gate0 + gx0);
            out[(size_t)b * Hdim + j0] =
                (1.0f - z0) * vt0 + 0.1f * (rec0 + mx0);
            float z1 = 0.1f * sigf(gate1 + gx1);
            out[(size_t)b * Hdim + j0 + 1] =
                (1.0f - z1) * vt1 + 0.1f * (rec1 + mx1);
        }
    }
}

extern "C" void kernel_launch(void* const* d_in, const int* in_sizes, int n_in,
                              void* d_out, int out_size, void* d_ws, size_t ws_size,
                              hipStream_t stream) {
    const float* x       = (const float*)d_in[0];   // (I,B)
    const float* v_t     = (const float*)d_in[1];   // (B,H)
    const float* X       = (const float*)d_in[2];   // (B,H,H)
    const float* U       = (const float*)d_in[3];   // (B,H,H)
    const float* raw_w_r = (const float*)d_in[4];   // (H,H)
    const float* p_r     = (const float*)d_in[5];   // (H,I)
    const float* b_r     = (const float*)d_in[6];   // (H,1)
    const float* g_z     = (const float*)d_in[7];   // (H,1)
    const float* c_x     = (const float*)d_in[8];   // (H,H)
    const float* c_u     = (const float*)d_in[9];   // (H,H)
    const float* c_U     = (const float*)d_in[10];  // (H,H)
    const float* a_exc   = (const float*)d_in[11];  // scalar
    const float* a_inh   = (const float*)d_in[12];  // scalar

    float* out = (float*)d_out;  // (B,H) fp32

    float* r_ws  = (float*)d_ws;              // B*H
    float* membx = r_ws + Bdim * Hdim;        // H*B
    float* gatex = membx + Hdim * Bdim;       // H*B

    pre_kernel<<<dim3(Hdim), dim3(Bdim), 0, stream>>>(
        x, v_t, p_r, b_r, g_z, r_ws, membx, gatex);

    main_kernel<<<dim3(Hdim), dim3(256), 0, stream>>>(
        X, U, raw_w_r, c_x, c_u, c_U, v_t, a_exc, a_inh,
        r_ws, membx, gatex, out);
}